// Round 4
// baseline (369.498 us; speedup 1.0000x reference)
//
#include <hip/hip_runtime.h>

// VQ-VAE nearest-codebook quantization via bf16 MFMA, occupancy-optimized.
// x: [64,256,32,32] fp32, emb: [512,256] fp32.
// out0 = codes NCHW, out1 = x, out2 = codes NCHW.
// s_k = ||e_k||^2 - 2 z.e_k (||z||^2 constant per position, dropped).
// 1024 blocks x 4 waves; wave owns 16 positions end-to-end (no tail sync).

#define D_  256
#define HW_ 1024
#define K_  512

typedef __attribute__((ext_vector_type(8))) short short8;
typedef __attribute__((ext_vector_type(4))) float f32x4;

__device__ unsigned short g_ebf[K_ * D_];  // emb bf16, row-major [k][d]
__device__ float g_e2[K_];                 // ||e_k||^2 fp32

__device__ __forceinline__ unsigned short f2bf(float f) {
    unsigned u = __float_as_uint(f);
    u += 0x7fffu + ((u >> 16) & 1u);       // RTNE
    return (unsigned short)(u >> 16);
}

__global__ void prep(const float* __restrict__ emb) {
    const int t   = threadIdx.x;
    const int row = blockIdx.x * 8 + (t >> 5);
    const int c0  = (t & 31) * 8;
    const float* rp = emb + row * D_ + c0;
    float4 a = *(const float4*)rp;
    float4 b = *(const float4*)(rp + 4);
    short8 v;
    v[0] = (short)f2bf(a.x); v[1] = (short)f2bf(a.y);
    v[2] = (short)f2bf(a.z); v[3] = (short)f2bf(a.w);
    v[4] = (short)f2bf(b.x); v[5] = (short)f2bf(b.y);
    v[6] = (short)f2bf(b.z); v[7] = (short)f2bf(b.w);
    *(short8*)(g_ebf + row * D_ + c0) = v;
    float ps = a.x*a.x + a.y*a.y + a.z*a.z + a.w*a.w
             + b.x*b.x + b.y*b.y + b.z*b.z + b.w*b.w;
    ps += __shfl_xor(ps, 1);  ps += __shfl_xor(ps, 2);
    ps += __shfl_xor(ps, 4);  ps += __shfl_xor(ps, 8);
    ps += __shfl_xor(ps, 16);
    if ((t & 31) == 0) g_e2[row] = ps;
}

__global__ __launch_bounds__(256, 4)
void vq_main(const float* __restrict__ x, const float* __restrict__ emb,
             float* __restrict__ out0, float* __restrict__ out1,
             float* __restrict__ out2) {
    __shared__ float zc[2][32][68];   // double-buffered 32d x 64pos chunk (pad 68)

    const int t   = threadIdx.x;
    const int w   = t >> 6;
    const int l   = t & 63;
    const int lq  = l >> 4;           // quadrant 0..3
    const int lp  = l & 15;           // position-in-tile
    const int blk = blockIdx.x;
    const int b   = blk >> 4;         // batch
    const int hw0 = (blk & 15) << 6;  // 64-position window
    const float* xb = x    + ((size_t)b * D_) * HW_ + hw0;
    float*       o1 = out1 + ((size_t)b * D_) * HW_ + hw0;

    const int d2a = (t >> 4);         // staging row (it=0): 0..15
    const int q4  = (t & 15) << 2;    // staging col: 0..60

    // ---- phase 1: stage x chunks (32d x 64pos), fused out1 copy, build B-frags ----
    {
#pragma unroll
        for (int it = 0; it < 2; ++it) {
            const int d2 = it * 16 + d2a;
            f32x4 v = *(const f32x4*)&xb[(size_t)d2 * HW_ + q4];
            __builtin_nontemporal_store(v, (f32x4*)&o1[(size_t)d2 * HW_ + q4]);
            *(f32x4*)&zc[0][d2][q4] = v;
        }
    }
    __syncthreads();

    short8 zb[8];
    for (int g = 0; g < 8; ++g) {
        f32x4 v0, v1;
        if (g < 7) {
            const int dr = 32 * (g + 1);
            v0 = *(const f32x4*)&xb[(size_t)(dr + d2a) * HW_ + q4];
            v1 = *(const f32x4*)&xb[(size_t)(dr + 16 + d2a) * HW_ + q4];
            __builtin_nontemporal_store(v0, (f32x4*)&o1[(size_t)(dr + d2a) * HW_ + q4]);
            __builtin_nontemporal_store(v1, (f32x4*)&o1[(size_t)(dr + 16 + d2a) * HW_ + q4]);
        }
        // extract this wave's B-frag for chunk g (pos = 16w + lp, k = lq*8+j)
        {
            short8 f;
#pragma unroll
            for (int j = 0; j < 8; ++j)
                f[j] = (short)f2bf(zc[g & 1][lq * 8 + j][16 * w + lp]);
            zb[g] = f;
        }
        if (g < 7) {
            *(f32x4*)&zc[(g + 1) & 1][d2a][q4]      = v0;
            *(f32x4*)&zc[(g + 1) & 1][16 + d2a][q4] = v1;
        }
        __syncthreads();
    }

    // ---- phase 2: 32 code-tiles of 16 vs this wave's 16 positions ----
    float minv = 3.0e38f;
    int   mini = 0;
    short8 ea[8], eb[8];
    f32x4  e2a, e2b;

#define LOADE(buf, e2r, ct) do {                                              \
        const unsigned short* _p = g_ebf + ((ct) * 16 + lp) * D_ + lq * 8;    \
        _Pragma("unroll")                                                     \
        for (int s = 0; s < 8; ++s) buf[s] = *(const short8*)(_p + s * 32);   \
        e2r = *(const f32x4*)(g_e2 + (ct) * 16 + lq * 4);                     \
    } while (0)

#define PROC(buf, e2v, ct) do {                                               \
        f32x4 a0 = {0.f, 0.f, 0.f, 0.f};                                      \
        _Pragma("unroll")                                                     \
        for (int s = 0; s < 8; ++s)                                           \
            a0 = __builtin_amdgcn_mfma_f32_16x16x32_bf16(buf[s], zb[s], a0, 0, 0, 0); \
        _Pragma("unroll")                                                     \
        for (int r = 0; r < 4; ++r) {                                         \
            const int code = (ct) * 16 + lq * 4 + r;                          \
            const float s0 = e2v[r] - 2.0f * a0[r];                           \
            if (s0 < minv) { minv = s0; mini = code; }                        \
        }                                                                     \
    } while (0)

    LOADE(ea, e2a, 0);
    for (int c = 0; c < 32; c += 2) {
        LOADE(eb, e2b, c + 1);
        PROC(ea, e2a, c);
        const int cn = (c + 2 < 32) ? (c + 2) : 0;
        LOADE(ea, e2a, cn);
        PROC(eb, e2b, c + 1);
    }

    // cross-quadrant argmin merge: lanes {l, l^16, l^32, l^48} share column lp
    {
        float ov; int oi;
        ov = __shfl_xor(minv, 16); oi = __shfl_xor(mini, 16);
        if (ov < minv || (ov == minv && oi < mini)) { minv = ov; mini = oi; }
        ov = __shfl_xor(minv, 32); oi = __shfl_xor(mini, 32);
        if (ov < minv || (ov == minv && oi < mini)) { minv = ov; mini = oi; }
    }
    // now every lane holds the argmin for its position lp

    // ---- epilogue (per-wave, no barrier): out0/out2 = emb[mini] scattered NCHW ----
    {
        const float* erow = emb + (size_t)mini * D_;
        float* p0 = out0 + ((size_t)b * D_) * HW_ + hw0 + 16 * w + lp;
        float* p2 = out2 + ((size_t)b * D_) * HW_ + hw0 + 16 * w + lp;
#pragma unroll 4
        for (int i = 0; i < 16; ++i) {
            const int d = lq * 4 + i * 16;
            f32x4 v = *(const f32x4*)&erow[d];
            __builtin_nontemporal_store(v.x, &p0[(size_t)(d + 0) * HW_]);
            __builtin_nontemporal_store(v.y, &p0[(size_t)(d + 1) * HW_]);
            __builtin_nontemporal_store(v.z, &p0[(size_t)(d + 2) * HW_]);
            __builtin_nontemporal_store(v.w, &p0[(size_t)(d + 3) * HW_]);
            __builtin_nontemporal_store(v.x, &p2[(size_t)(d + 0) * HW_]);
            __builtin_nontemporal_store(v.y, &p2[(size_t)(d + 1) * HW_]);
            __builtin_nontemporal_store(v.z, &p2[(size_t)(d + 2) * HW_]);
            __builtin_nontemporal_store(v.w, &p2[(size_t)(d + 3) * HW_]);
        }
    }
}

extern "C" void kernel_launch(void* const* d_in, const int* in_sizes, int n_in,
                              void* d_out, int out_size, void* d_ws, size_t ws_size,
                              hipStream_t stream) {
    const float* x   = (const float*)d_in[0];
    const float* emb = (const float*)d_in[1];
    float* out0 = (float*)d_out;
    float* out1 = out0 + (size_t)16777216;
    float* out2 = out0 + (size_t)33554432;

    prep<<<64, 256, 0, stream>>>(emb);
    vq_main<<<1024, 256, 0, stream>>>(x, emb, out0, out1, out2);
}